// Round 5
// baseline (261.902 us; speedup 1.0000x reference)
//
#include <hip/hip_runtime.h>

// NCC weight loss — fused z-streaming kernel, phase-balanced across all waves.
// Pipeline per step t (2 barriers):
//   Phase1: B(t-1): zsL -> sx   (480 tasks, all threads)
//           C2(t-2): sS + Wm -> acc (wave 3)
//   Phase2: A(t): global/regs -> zsL (216 threads, pair-column z-rings)
//           C1(t-1): sx -> sS  (320 tasks, all threads)
// Dims fixed: (N=2, C=1, D=160, H=192, W=224), win=5, fp32.
#define N_  2
#define D_  160
#define H_  192
#define W_  224
#define TW  32
#define TH  8
#define ZCH 32
#define NZC (D_/ZCH)      // 5
#define RS  40            // padded LDS row stride (floats): (8r+4g)%32 -> 2-way only
#define QS  (12*RS)       // per-quantity plane stride (floats)
#define HW_ (H_*W_)
#define TOT (N_*D_*H_*W_) // 13,762,560

__global__ __launch_bounds__(256) void ncc_kernel(
    const float* __restrict__ I, const float* __restrict__ J,
    const float* __restrict__ Wm, float* __restrict__ out)
{
    __shared__ __align__(16) float zsL[5 * QS];      // z-summed quantity planes (12x40 rows)
    __shared__ __align__(16) float sx [5 * QS];      // x-box-summed planes
    __shared__ __align__(16) float sS [5 * 8 * RS];  // staged 2D window sums [a][q][4s]
    __shared__ float red[4];

    const int tid = threadIdx.x;
    const int bx = blockIdx.x, by = blockIdx.y;
    const int n  = blockIdx.z / NZC;
    const int c0 = (blockIdx.z % NZC) * ZCH;
    const int wbase = bx * TW - 2;
    const int hbase = by * TH - 2;
    const int nb = n * (D_ * HW_);

    // ---- Phase A ownership: 216 threads own 2 adjacent halo columns ----
    const bool aAct = tid < 216;
    const int arow = tid / 18;           // 0..11
    const int ag   = tid % 18;           // 0..17
    const int ah   = hbase + arow;
    const int aw0  = wbase + 2 * ag;     // even; in-range => aw0+1 in range (W even)
    const bool aok = aAct && ((unsigned)ah < (unsigned)H_) && ((unsigned)aw0 < (unsigned)W_);
    const int aoff = ah * W_ + aw0;

    float rI0[5], rJ0[5], rI1[5], rJ1[5];
    float zs0[5], zs1[5];
#pragma unroll
    for (int k = 0; k < 5; ++k) { rI0[k]=0.f; rJ0[k]=0.f; rI1[k]=0.f; rJ1[k]=0.f; }
#pragma unroll
    for (int a = 0; a < 5; ++a) { zs0[a]=0.f; zs1[a]=0.f; }

    // ---- C2 ownership: wave 3, one float4 output each ----
    const bool c2Act = tid >= 192;
    const int o2 = tid - 192;            // 0..63
    const int q2 = o2 >> 3;              // out row 0..7
    const int s2 = o2 & 7;               // col group 0..7
    const int coff = (by * TH + q2) * W_ + (bx * TW + 4 * s2);

    // ---- prefetched globals ----
    float2 pI = make_float2(0.f, 0.f), pJ = make_float2(0.f, 0.f);
    {
        const int z0 = c0 - 2;
        if (aok && z0 >= 0) {
            const int g = nb + z0 * HW_ + aoff;
            pI = *(const float2*)&I[g];
            pJ = *(const float2*)&J[g];
        }
    }
    float4 pWm = make_float4(0.f, 0.f, 0.f, 0.f);
    if (c2Act) pWm = *(const float4*)&Wm[nb + c0 * HW_ + coff];

    float acc = 0.f;
    const float inv125 = 1.0f / 125.0f;

    // B task: x box-sum (36 -> 32) for (quantity a, row r, col-group g)
    auto do_b = [&](int task) {
        const int a  = task / 96;
        const int rg = task - a * 96;
        const int r  = rg >> 3;
        const int g  = rg & 7;
        const float* p = &zsL[a * QS + r * RS + 4 * g];
        const float4 v0 = *(const float4*)p;
        const float4 v1 = *(const float4*)(p + 4);
        const float m  = v0.y + v0.z + v0.w;
        const float u1 = v1.x + v1.y;
        const float u2 = u1 + v1.z;
        float4 o;
        o.x = v0.x + m + v1.x;
        o.y = m + u1;
        o.z = (v0.z + v0.w) + u2;
        o.w = v0.w + (u2 + v1.w);
        *(float4*)&sx[a * QS + r * RS + 4 * g] = o;
    };

    // C1 task: y box-sum (5 rows) for (quantity a, output-float4 o), stage to sS
    auto do_c1 = [&](int task) {
        const int a = task >> 6;
        const int o = task & 63;
        const int q = o >> 3;
        const int s = o & 7;
        const float* p = &sx[a * QS + q * RS + 4 * s];
        float4 v = *(const float4*)p;
#pragma unroll
        for (int k = 1; k < 5; ++k) {
            const float4 w = *(const float4*)(p + k * RS);
            v.x += w.x; v.y += w.y; v.z += w.z; v.w += w.w;
        }
        *(float4*)&sS[a * (8 * RS) + q * RS + 4 * s] = v;
    };

    for (int t = 0; t <= ZCH + 5; ++t) {

        // ---------------- Phase 1: B(t-1)  ||  C2(t-2) ----------------
        if (t >= 5 && t <= ZCH + 4) {
            do_b(tid);
            if (tid < 224) do_b(256 + tid);
        }
        if (t >= 6 && c2Act) {
            float4 S[5];
#pragma unroll
            for (int a = 0; a < 5; ++a)
                S[a] = *(const float4*)&sS[a * (8 * RS) + q2 * RS + 4 * s2];
            const float4 wm = pWm;
            const int zo = c0 + t - 6;
            if (t <= ZCH + 4)
                pWm = *(const float4*)&Wm[nb + (zo + 1) * HW_ + coff];
            {
                const float cr = S[4].x - S[0].x * S[1].x * inv125;
                const float vi = S[2].x - S[0].x * S[0].x * inv125;
                const float vj = S[3].x - S[1].x * S[1].x * inv125;
                acc += wm.x * (cr * cr) * __builtin_amdgcn_rcpf(vi * vj + 1e-8f);
            }
            {
                const float cr = S[4].y - S[0].y * S[1].y * inv125;
                const float vi = S[2].y - S[0].y * S[0].y * inv125;
                const float vj = S[3].y - S[1].y * S[1].y * inv125;
                acc += wm.y * (cr * cr) * __builtin_amdgcn_rcpf(vi * vj + 1e-8f);
            }
            {
                const float cr = S[4].z - S[0].z * S[1].z * inv125;
                const float vi = S[2].z - S[0].z * S[0].z * inv125;
                const float vj = S[3].z - S[1].z * S[1].z * inv125;
                acc += wm.z * (cr * cr) * __builtin_amdgcn_rcpf(vi * vj + 1e-8f);
            }
            {
                const float cr = S[4].w - S[0].w * S[1].w * inv125;
                const float vi = S[2].w - S[0].w * S[0].w * inv125;
                const float vj = S[3].w - S[1].w * S[1].w * inv125;
                acc += wm.w * (cr * cr) * __builtin_amdgcn_rcpf(vi * vj + 1e-8f);
            }
        }
        __syncthreads();   // B done with zsL (A overwrites next); sx ready for C1

        // ---------------- Phase 2: A(t)  ||  C1(t-1) ----------------
        if (t <= ZCH + 3 && aAct) {
            const float iv0 = pI.x, iv1 = pI.y, jv0 = pJ.x, jv1 = pJ.y;

            float2 nI = make_float2(0.f, 0.f), nJ = make_float2(0.f, 0.f);
            const int zn = c0 - 1 + t;
            if (t <= ZCH + 2 && aok && (unsigned)zn < (unsigned)D_) {
                const int g = nb + zn * HW_ + aoff;
                nI = *(const float2*)&I[g];
                nJ = *(const float2*)&J[g];
            }
            pI = nI; pJ = nJ;

            {   // column 0
                const float oi = rI0[0], oj = rJ0[0];
                zs0[0] += iv0 - oi;
                zs0[1] += jv0 - oj;
                zs0[2] += iv0*iv0 - oi*oi;
                zs0[3] += jv0*jv0 - oj*oj;
                zs0[4] += iv0*jv0 - oi*oj;
#pragma unroll
                for (int k = 0; k < 4; ++k) { rI0[k]=rI0[k+1]; rJ0[k]=rJ0[k+1]; }
                rI0[4] = iv0; rJ0[4] = jv0;
            }
            {   // column 1
                const float oi = rI1[0], oj = rJ1[0];
                zs1[0] += iv1 - oi;
                zs1[1] += jv1 - oj;
                zs1[2] += iv1*iv1 - oi*oi;
                zs1[3] += jv1*jv1 - oj*oj;
                zs1[4] += iv1*jv1 - oi*oj;
#pragma unroll
                for (int k = 0; k < 4; ++k) { rI1[k]=rI1[k+1]; rJ1[k]=rJ1[k+1]; }
                rI1[4] = iv1; rJ1[4] = jv1;
            }
#pragma unroll
            for (int a = 0; a < 5; ++a)
                *(float2*)&zsL[a * QS + arow * RS + 2 * ag] = make_float2(zs0[a], zs1[a]);
        }
        if (t >= 5 && t <= ZCH + 4) {
            do_c1(tid);
            if (tid < 64) do_c1(256 + tid);
        }
        __syncthreads();   // zsL(t) ready for B(t+1); sS(t-1) ready for C2(t+1)
    }

    // Block reduction
#pragma unroll
    for (int off = 32; off > 0; off >>= 1)
        acc += __shfl_down(acc, off, 64);
    const int wave = tid >> 6;
    const int lane = tid & 63;
    if (lane == 0) red[wave] = acc;
    __syncthreads();
    if (tid == 0) {
        const float t = red[0] + red[1] + red[2] + red[3];
        atomicAdd(out, t * (-1.0f / (float)TOT));
    }
}

extern "C" void kernel_launch(void* const* d_in, const int* in_sizes, int n_in,
                              void* d_out, int out_size, void* d_ws, size_t ws_size,
                              hipStream_t stream)
{
    const float* I  = (const float*)d_in[0];
    const float* J  = (const float*)d_in[1];
    const float* Wm = (const float*)d_in[2];
    float* out = (float*)d_out;

    hipMemsetAsync(out, 0, sizeof(float), stream);

    dim3 grid(W_ / TW, H_ / TH, N_ * NZC);  // (7, 24, 10) = 1680 blocks
    dim3 block(256);
    hipLaunchKernelGGL(ncc_kernel, grid, block, 0, stream, I, J, Wm, out);
}

// Round 7
// 251.186 us; speedup vs baseline: 1.0427x; 1.0427x over previous
//
#include <hip/hip_runtime.h>

// NCC weight loss — fused z-streaming kernel (exact r2 structure / codegen,
// proven 60-VGPR no-spill) with finer z-chunks for full CU co-residency:
// ZCH=20 -> 2688 blocks (10.5/CU), ~8 blocks resident/CU.
// Dims fixed: (N=2, C=1, D=160, H=192, W=224), win=5, fp32.
#define N_  2
#define D_  160
#define H_  192
#define W_  224
#define TW  32            // output tile width (x)
#define TH  8             // output tile height (y)
#define ZCH 20            // z-chunk per block
#define NZC (D_/ZCH)      // 8
#define HWH (TW+4)        // 36 halo width
#define HHH (TH+4)        // 12 halo height
#define TOT (N_*D_*H_*W_) // 13,762,560

__global__ __launch_bounds__(256) void ncc_kernel(
    const float* __restrict__ I, const float* __restrict__ J,
    const float* __restrict__ Wm, float* __restrict__ out)
{
    __shared__ __align__(16) float zsL[5][HHH][HWH]; // z-summed quantity planes
    __shared__ __align__(16) float sx [5][HHH][TW];  // x-box-summed planes
    __shared__ float red[4];

    const int tid = threadIdx.x;
    const int bx = blockIdx.x, by = blockIdx.y;
    const int n  = blockIdx.z / NZC;
    const int c0 = (blockIdx.z % NZC) * ZCH;
    const int wbase = bx * TW - 2;
    const int hbase = by * TH - 2;

    // ---- Phase A ownership: 216 threads own 2 adjacent halo columns ----
    const bool aAct = tid < 216;
    const int arow = tid / 18;          // 0..11
    const int ag   = tid % 18;          // 0..17
    const int ah   = hbase + arow;
    const int aw0  = wbase + 2 * ag;    // even -> float2-aligned in global
    const bool hok  = (unsigned)ah < (unsigned)H_;
    const bool w0ok = (unsigned)aw0 < (unsigned)W_;
    const bool w1ok = (unsigned)(aw0 + 1) < (unsigned)W_;
    const bool v2   = w0ok && w1ok;

    // per-column z-ring of raw I,J (5 deep) + incremental z-sums of 5 quantities
    float rI0[5], rJ0[5], rI1[5], rJ1[5];
    float zs0[5], zs1[5];
#pragma unroll
    for (int k = 0; k < 5; ++k) { rI0[k]=0.f; rJ0[k]=0.f; rI1[k]=0.f; rJ1[k]=0.f; }
#pragma unroll
    for (int a = 0; a < 5; ++a) { zs0[a]=0.f; zs1[a]=0.f; }

    // ---- Phase B ownership: 96 threads, 4 x-outputs each ----
    const bool bAct = tid < 96;
    const int brow = tid >> 3;          // 0..11
    const int bx0  = (tid & 7) * 4;     // 0,4,...,28

    // ---- Phase C ownership: 64 threads, 4 outputs each ----
    const bool cAct = tid < 64;
    const int cty = tid >> 3;           // 0..7
    const int cx0 = (tid & 7) * 4;      // 0..28
    const int ch  = by * TH + cty;
    const int cw  = bx * TW + cx0;      // multiple of 4 -> float4-aligned

    float acc = 0.f;
    const float inv125 = 1.0f / 125.0f;

    // s = 0 .. ZCH+3: plane z = c0-2+s in [c0-2, c0+ZCH+1];
    // output zo = z-2 = c0-4+s, emitted for s >= 4 -> zo in [c0, c0+ZCH-1].
    for (int s = 0; s < ZCH + 4; ++s) {
        const int z = c0 - 2 + s;
        const bool zin = (unsigned)z < (unsigned)D_;

        // ---------- Phase A: load plane z, update register z-sums, stage to LDS
        if (aAct) {
            float iv0=0.f, iv1=0.f, jv0=0.f, jv1=0.f;
            if (zin && hok) {
                const int base = ((n * D_ + z) * H_ + ah) * W_;
                if (v2) {
                    const float2 i2 = *(const float2*)&I[base + aw0];
                    const float2 j2 = *(const float2*)&J[base + aw0];
                    iv0 = i2.x; iv1 = i2.y; jv0 = j2.x; jv1 = j2.y;
                } else {
                    if (w0ok) { iv0 = I[base + aw0];     jv0 = J[base + aw0]; }
                    if (w1ok) { iv1 = I[base + aw0 + 1]; jv1 = J[base + aw0 + 1]; }
                }
            }
            {   // column 0: subtract oldest, add newest, shift ring
                const float oi = rI0[0], oj = rJ0[0];
                zs0[0] += iv0 - oi;
                zs0[1] += jv0 - oj;
                zs0[2] += iv0*iv0 - oi*oi;
                zs0[3] += jv0*jv0 - oj*oj;
                zs0[4] += iv0*jv0 - oi*oj;
#pragma unroll
                for (int k = 0; k < 4; ++k) { rI0[k]=rI0[k+1]; rJ0[k]=rJ0[k+1]; }
                rI0[4] = iv0; rJ0[4] = jv0;
            }
            {   // column 1
                const float oi = rI1[0], oj = rJ1[0];
                zs1[0] += iv1 - oi;
                zs1[1] += jv1 - oj;
                zs1[2] += iv1*iv1 - oi*oi;
                zs1[3] += jv1*jv1 - oj*oj;
                zs1[4] += iv1*jv1 - oi*oj;
#pragma unroll
                for (int k = 0; k < 4; ++k) { rI1[k]=rI1[k+1]; rJ1[k]=rJ1[k+1]; }
                rI1[4] = iv1; rJ1[4] = jv1;
            }
#pragma unroll
            for (int a = 0; a < 5; ++a) {
                *(float2*)&zsL[a][arow][2*ag] = make_float2(zs0[a], zs1[a]);
            }
        }
        __syncthreads();

        // ---------- Phase B: x box-sum (36 -> 32), 4 outputs per thread
        if (bAct) {
#pragma unroll
            for (int a = 0; a < 5; ++a) {
                const float4 v0 = *(const float4*)&zsL[a][brow][bx0];
                const float4 v1 = *(const float4*)&zsL[a][brow][bx0 + 4];
                const float m  = v0.y + v0.z + v0.w;
                const float u1 = v1.x + v1.y;
                const float u2 = u1 + v1.z;
                const float o0 = v0.x + m + v1.x;
                const float o1 = m + u1;
                const float o2 = (v0.z + v0.w) + u2;
                const float o3 = v0.w + (u2 + v1.w);
                *(float4*)&sx[a][brow][bx0] = make_float4(o0, o1, o2, o3);
            }
        }
        __syncthreads();

        // ---------- Phase C: y box-sum + cc + weighted accumulate, 4 outputs/thread
        const int zo = z - 2;
        if (cAct && zo >= c0) {
            float4 S[5];
#pragma unroll
            for (int a = 0; a < 5; ++a) {
                float4 v = *(const float4*)&sx[a][cty][cx0];
#pragma unroll
                for (int k = 1; k < 5; ++k) {
                    const float4 w = *(const float4*)&sx[a][cty + k][cx0];
                    v.x += w.x; v.y += w.y; v.z += w.z; v.w += w.w;
                }
                S[a] = v;
            }
            const float4 wm = *(const float4*)&Wm[((n * D_ + zo) * H_ + ch) * W_ + cw];
            {
                const float cr = S[4].x - S[0].x * S[1].x * inv125;
                const float vi = S[2].x - S[0].x * S[0].x * inv125;
                const float vj = S[3].x - S[1].x * S[1].x * inv125;
                acc += wm.x * (cr * cr) * __builtin_amdgcn_rcpf(vi * vj + 1e-8f);
            }
            {
                const float cr = S[4].y - S[0].y * S[1].y * inv125;
                const float vi = S[2].y - S[0].y * S[0].y * inv125;
                const float vj = S[3].y - S[1].y * S[1].y * inv125;
                acc += wm.y * (cr * cr) * __builtin_amdgcn_rcpf(vi * vj + 1e-8f);
            }
            {
                const float cr = S[4].z - S[0].z * S[1].z * inv125;
                const float vi = S[2].z - S[0].z * S[0].z * inv125;
                const float vj = S[3].z - S[1].z * S[1].z * inv125;
                acc += wm.z * (cr * cr) * __builtin_amdgcn_rcpf(vi * vj + 1e-8f);
            }
            {
                const float cr = S[4].w - S[0].w * S[1].w * inv125;
                const float vi = S[2].w - S[0].w * S[0].w * inv125;
                const float vj = S[3].w - S[1].w * S[1].w * inv125;
                acc += wm.w * (cr * cr) * __builtin_amdgcn_rcpf(vi * vj + 1e-8f);
            }
        }
        // next Phase A writes zsL (not read in C); post-B barrier protects sx
    }

    // Block reduction: wave64 shuffle, then cross-wave via LDS
#pragma unroll
    for (int off = 32; off > 0; off >>= 1)
        acc += __shfl_down(acc, off, 64);
    const int wave = tid >> 6;
    const int lane = tid & 63;
    if (lane == 0) red[wave] = acc;
    __syncthreads();
    if (tid == 0) {
        const float t = red[0] + red[1] + red[2] + red[3];
        atomicAdd(out, t * (-1.0f / (float)TOT));
    }
}

extern "C" void kernel_launch(void* const* d_in, const int* in_sizes, int n_in,
                              void* d_out, int out_size, void* d_ws, size_t ws_size,
                              hipStream_t stream)
{
    const float* I  = (const float*)d_in[0];
    const float* J  = (const float*)d_in[1];
    const float* Wm = (const float*)d_in[2];
    float* out = (float*)d_out;

    hipMemsetAsync(out, 0, sizeof(float), stream);

    dim3 grid(W_ / TW, H_ / TH, N_ * NZC);  // (7, 24, 16) = 2688 blocks
    dim3 block(256);
    hipLaunchKernelGGL(ncc_kernel, grid, block, 0, stream, I, J, Wm, out);
}